// Round 5
// baseline (848.179 us; speedup 1.0000x reference)
//
#include <hip/hip_runtime.h>
#include <stdint.h>

typedef unsigned short u16;
typedef uint32_t u32;

__device__ __forceinline__ float bf2f(u16 u){ return __uint_as_float(((u32)u) << 16); }
__device__ __forceinline__ u16 f2bf(float f){
    u32 u = __float_as_uint(f);
    u += 0x7FFFu + ((u >> 16) & 1u);   // round-to-nearest-even
    return (u16)(u >> 16);
}

// ---------------------------------------------------------------------------
// f32 VALU NT GEMM: C[m,n] = sum_k A[m,k]*B[n,k] (+bias) (+softplus)
// 64x64 tile, BK=16, 256 threads, 4x4 outputs/thread via LDS outer product.
// EPI: 0 none, 1 +bias, 2 +bias then softplus.  OUTBF: write bf16 else f32.
// ---------------------------------------------------------------------------
template<int EPI, bool OUTBF>
__global__ __launch_bounds__(256)
void gemm_nt_f32(const float* __restrict__ A, const float* __restrict__ B,
                 const float* __restrict__ bias, void* __restrict__ Cout,
                 int M, int N, int K, int lda, int ldb, int ldc)
{
    __shared__ float As[16][68];   // [k][m]
    __shared__ float Bs[16][68];   // [k][n]
    const int tid = threadIdx.x;
    const int nbn = (N + 63) >> 6;
    const int bm = blockIdx.x / nbn, bn = blockIdx.x % nbn;
    const int m0 = bm*64, n0 = bn*64;
    const int tx = tid & 15, ty = tid >> 4;
    const int sr = tid >> 2;            // 0..63 tile row
    const int sc = (tid & 3) * 4;       // k offset 0/4/8/12

    float acc[4][4];
    #pragma unroll
    for(int i=0;i<4;i++)
        #pragma unroll
        for(int j=0;j<4;j++) acc[i][j] = 0.f;

    for(int k0 = 0; k0 < K; k0 += 16){
        __syncthreads();
        float4 av = *(const float4*)(A + (size_t)(m0+sr)*lda + k0 + sc);
        float4 bv = (n0+sr < N) ? *(const float4*)(B + (size_t)(n0+sr)*ldb + k0 + sc)
                                : make_float4(0.f,0.f,0.f,0.f);
        As[sc+0][sr]=av.x; As[sc+1][sr]=av.y; As[sc+2][sr]=av.z; As[sc+3][sr]=av.w;
        Bs[sc+0][sr]=bv.x; Bs[sc+1][sr]=bv.y; Bs[sc+2][sr]=bv.z; Bs[sc+3][sr]=bv.w;
        __syncthreads();
        #pragma unroll
        for(int kk=0;kk<16;kk++){
            float a0=As[kk][ty*4+0], a1=As[kk][ty*4+1], a2=As[kk][ty*4+2], a3=As[kk][ty*4+3];
            float b0=Bs[kk][tx*4+0], b1=Bs[kk][tx*4+1], b2=Bs[kk][tx*4+2], b3=Bs[kk][tx*4+3];
            acc[0][0]+=a0*b0; acc[0][1]+=a0*b1; acc[0][2]+=a0*b2; acc[0][3]+=a0*b3;
            acc[1][0]+=a1*b0; acc[1][1]+=a1*b1; acc[1][2]+=a1*b2; acc[1][3]+=a1*b3;
            acc[2][0]+=a2*b0; acc[2][1]+=a2*b1; acc[2][2]+=a2*b2; acc[2][3]+=a2*b3;
            acc[3][0]+=a3*b0; acc[3][1]+=a3*b1; acc[3][2]+=a3*b2; acc[3][3]+=a3*b3;
        }
    }

    #pragma unroll
    for(int i=0;i<4;i++){
        const int row = m0 + ty*4 + i;
        #pragma unroll
        for(int j=0;j<4;j++){
            const int col = n0 + tx*4 + j;
            if(col < N){
                float v = acc[i][j];
                if(EPI >= 1) v += bias[col];
                if(EPI == 2) v = (v > 0.f) ? (v + log1pf(__expf(-v))) : log1pf(__expf(v));
                if(OUTBF) ((u16*)Cout)[(size_t)row*ldc + col] = f2bf(v);
                else      ((float*)Cout)[(size_t)row*ldc + col] = v;
            }
        }
    }
}

// ---------------------------------------------------------------------------
// Depthwise causal conv (k=4) + bias + silu. xin bf16 [u|z] rows of 1024 -> u2 f32.
// ---------------------------------------------------------------------------
__global__ __launch_bounds__(256)
void conv_silu(const u16* __restrict__ xin, const float* __restrict__ conv_w,
               const float* __restrict__ conv_b, float* __restrict__ u2)
{
    const int idx = blockIdx.x*256 + threadIdx.x;   // 8*2048*512
    const int d = idx & 511;
    const int m = idx >> 9;
    const int l = m & 2047;
    const u16* base = xin + (size_t)m*1024 + d;
    float acc = conv_b[d];
    const float w0 = conv_w[d*4+0];
    const float w1 = conv_w[d*4+1];
    const float w2 = conv_w[d*4+2];
    const float w3 = conv_w[d*4+3];
    if(l >= 3) acc += bf2f(base[-3*1024])*w0;
    if(l >= 2) acc += bf2f(base[-2*1024])*w1;
    if(l >= 1) acc += bf2f(base[-1*1024])*w2;
    acc += bf2f(base[0])*w3;
    u2[idx] = acc / (1.f + __expf(-acc));
}

// ---------------------------------------------------------------------------
// Chunked selective scan: 32 chunks x 64 steps. blocks=(b,c), 512 thr = d.
// ---------------------------------------------------------------------------
__global__ __launch_bounds__(512)
void scan_a(const u16* __restrict__ dtb, const float* __restrict__ u2,
            const float* __restrict__ xdbc, const float* __restrict__ A_log,
            float* __restrict__ P, float* __restrict__ S)
{
    const int b = blockIdx.x >> 5, c = blockIdx.x & 31;
    const int d = threadIdx.x;
    const int m0 = b*2048 + c*64;
    __shared__ float Bsh[64][16];
    for(int i = d; i < 1024; i += 512){
        const int tt = i >> 4, n = i & 15;
        Bsh[tt][n] = xdbc[(size_t)(m0+tt)*48 + 16 + n];
    }
    __syncthreads();
    float An[16];
    #pragma unroll
    for(int n=0;n<16;n++) An[n] = -__expf(A_log[d*16+n]);
    float h[16];
    #pragma unroll
    for(int n=0;n<16;n++) h[n] = 0.f;
    float dts = 0.f;
    for(int t=0;t<64;t++){
        const int m = m0 + t;
        const float dtv = bf2f(dtb[(size_t)m*512 + d]);
        const float uv  = u2[(size_t)m*512 + d];
        const float du  = dtv*uv;
        dts += dtv;
        #pragma unroll
        for(int n=0;n<16;n++){
            h[n] = __expf(An[n]*dtv)*h[n] + du*Bsh[t][n];
        }
    }
    const size_t o = ((size_t)(b*32 + c)*512 + d)*16;
    #pragma unroll
    for(int n=0;n<16;n++){ P[o+n] = __expf(An[n]*dts); S[o+n] = h[n]; }
}

__global__ __launch_bounds__(256)
void scan_b(const float* __restrict__ P, const float* __restrict__ S,
            float* __restrict__ Hin)
{
    const int gid = blockIdx.x*256 + threadIdx.x;   // 65536 = 8 * 8192
    const int b = gid >> 13;
    const int dn = gid & 8191;
    float h = 0.f;
    for(int c=0;c<32;c++){
        const size_t o = (size_t)(b*32 + c)*8192 + dn;
        const float t = P[o]*h + S[o];
        Hin[o] = h;
        h = t;
    }
}

__global__ __launch_bounds__(512)
void scan_c(const u16* __restrict__ dtb, const float* __restrict__ u2,
            const float* __restrict__ xdbc, const u16* __restrict__ xin,
            const float* __restrict__ A_log, const float* __restrict__ Dp,
            const float* __restrict__ Hin, float* __restrict__ ypc)
{
    const int b = blockIdx.x >> 5, c = blockIdx.x & 31;
    const int d = threadIdx.x;
    const int m0 = b*2048 + c*64;
    __shared__ float Bsh[64][16];
    __shared__ float Csh[64][16];
    for(int i = d; i < 1024; i += 512){
        const int tt = i >> 4, n = i & 15;
        const size_t row = (size_t)(m0+tt)*48;
        Bsh[tt][n] = xdbc[row + 16 + n];
        Csh[tt][n] = xdbc[row + 32 + n];
    }
    __syncthreads();
    float An[16];
    #pragma unroll
    for(int n=0;n<16;n++) An[n] = -__expf(A_log[d*16+n]);
    const float Dpd = Dp[d];
    const size_t ho = ((size_t)(b*32 + c)*512 + d)*16;
    float h[16];
    #pragma unroll
    for(int n=0;n<16;n++) h[n] = Hin[ho+n];
    float ysum = 0.f;
    for(int t=0;t<64;t++){
        const int m = m0 + t;
        const float dtv = bf2f(dtb[(size_t)m*512 + d]);
        const float uv  = u2[(size_t)m*512 + d];
        const float du  = dtv*uv;
        float y = 0.f;
        #pragma unroll
        for(int n=0;n<16;n++){
            h[n] = __expf(An[n]*dtv)*h[n] + du*Bsh[t][n];
            y += h[n]*Csh[t][n];
        }
        y += uv*Dpd;
        const float zv = bf2f(xin[(size_t)m*1024 + 512 + d]);
        y *= zv / (1.f + __expf(-zv));   // * silu(z)
        ysum += y;
    }
    ypc[(size_t)(b*32 + c)*512 + d] = ysum;   // per-chunk partial, no atomics
}

// pooled[b,m] = (sum_c sum_l y)/2048 @ W_out[m,:]
__global__ __launch_bounds__(256)
void pool_proj(const float* __restrict__ ypc, const float* __restrict__ W_out,
               float* __restrict__ pooled)
{
    __shared__ float yp[512];
    const int b = blockIdx.x, m = threadIdx.x;
    for(int d = m; d < 512; d += 256){
        float s = 0.f;
        for(int c=0;c<32;c++) s += ypc[(size_t)(b*32 + c)*512 + d];
        yp[d] = s;
    }
    __syncthreads();
    const float* w = W_out + (size_t)m*512;
    float s = 0.f;
    for(int d=0; d<512; d++) s += yp[d]*w[d];
    pooled[b*256 + m] = s*(1.f/2048.f);
}

// ---------------------------------------------------------------------------
// Head stage, VALU, one block per batch row, 256 threads = output dim n.
// ---------------------------------------------------------------------------
template<bool FIRST>
__global__ __launch_bounds__(256)
void head_stage_v(const float* __restrict__ pooled, const float* __restrict__ curin,
                  const float* __restrict__ gw, const float* __restrict__ gb,
                  const float* __restrict__ Wv, const float* __restrict__ bv,
                  const float* __restrict__ Wo, const float* __restrict__ bo,
                  float* __restrict__ curout)
{
    const int b = blockIdx.x;       // 8
    const int n = threadIdx.x;      // 256
    __shared__ float sP[256], sC[256], sF[256], sV[256];
    sP[n] = pooled[b*256 + n];
    if(!FIRST) sC[n] = curin[b*256 + n];
    __syncthreads();

    float f;
    if(FIRST){
        f = sP[n];
    } else {
        float g = gb[n];
        const float* w = gw + (size_t)n*512;
        for(int k=0;k<256;k++) g += sC[k]*w[k];
        for(int k=0;k<256;k++) g += sP[k]*w[256+k];
        g = 1.f/(1.f + __expf(-g));
        f = g*sC[n] + (1.f - g)*sP[n];
    }
    sF[n] = f;
    __syncthreads();

    float v = bv[n];
    { const float* w = Wv + (size_t)n*256;
      for(int k=0;k<256;k++) v += sF[k]*w[k]; }
    sV[n] = v;
    __syncthreads();

    float o = bo[n];
    { const float* w = Wo + (size_t)n*256;
      for(int k=0;k<256;k++) o += sV[k]*w[k]; }
    curout[b*256 + n] = o;
}

// ---------------------------------------------------------------------------
// Classifier heads: out_i = feats[i] @ Wc_i^T + bc_i, concat flat, F32 out.
// ---------------------------------------------------------------------------
__global__ __launch_bounds__(256)
void classifier_k(const float* __restrict__ feats,
    const float* __restrict__ W0, const float* __restrict__ b0,
    const float* __restrict__ W1, const float* __restrict__ b1,
    const float* __restrict__ W2, const float* __restrict__ b2,
    const float* __restrict__ W3, const float* __restrict__ b3,
    const float* __restrict__ W4, const float* __restrict__ b4,
    const float* __restrict__ W5, const float* __restrict__ b5,
    float* __restrict__ out)
{
    const int tid = blockIdx.x*256 + threadIdx.x;
    if(tid >= 19320) return;
    const int b  = tid & 7;
    const int ic = tid >> 3;            // 0..2414
    int i, c, nc, ooff;
    const float *W, *bb;
    if(ic < 5)       { i=0; c=ic;      nc=5;    ooff=0;    W=W0; bb=b0; }
    else if(ic<35)   { i=1; c=ic-5;    nc=30;   ooff=40;   W=W1; bb=b1; }
    else if(ic<115)  { i=2; c=ic-35;   nc=80;   ooff=280;  W=W2; bb=b2; }
    else if(ic<315)  { i=3; c=ic-115;  nc=200;  ooff=920;  W=W3; bb=b3; }
    else if(ic<915)  { i=4; c=ic-315;  nc=600;  ooff=2520; W=W4; bb=b4; }
    else             { i=5; c=ic-915;  nc=1500; ooff=7320; W=W5; bb=b5; }
    const float* f = feats + ((size_t)i*8 + b)*256;
    const float* w = W + (size_t)c*256;
    float acc = bb[c];
    for(int m=0;m<256;m++) acc += f[m]*w[m];
    out[ooff + b*nc + c] = acc;      // FLOAT32 output (reference output dtype)
}

extern "C" void kernel_launch(void* const* d_in, const int* in_sizes, int n_in,
                              void* d_out, int out_size, void* d_ws, size_t ws_size,
                              hipStream_t stream)
{
    // dict-insertion order, f32 (confirmed: in_sizes[0]==16777216 path, rounds 3/4)
    const float* x         = (const float*)d_in[0];
    const float* W_proj    = (const float*)d_in[1];
    const float* b_proj    = (const float*)d_in[2];
    const float* W_in      = (const float*)d_in[3];
    const float* conv_w    = (const float*)d_in[4];
    const float* conv_b    = (const float*)d_in[5];
    const float* W_xp      = (const float*)d_in[6];
    const float* W_dt      = (const float*)d_in[7];
    const float* b_dt      = (const float*)d_in[8];
    const float* A_log     = (const float*)d_in[9];
    const float* Dp        = (const float*)d_in[10];
    const float* W_out     = (const float*)d_in[11];
    const float* mha_in_w  = (const float*)d_in[12];
    const float* mha_in_b  = (const float*)d_in[13];
    const float* mha_out_w = (const float*)d_in[14];
    const float* mha_out_b = (const float*)d_in[15];
    const float* gate_w    = (const float*)d_in[16];
    const float* gate_b    = (const float*)d_in[17];

    char* ws = (char*)d_ws;
    float* h      = (float*)(ws + 0);           // 16 MB f32 (dead after gemm2)
    float* P      = (float*)(ws + 0);           // alias h: first 8 MB
    float* S      = (float*)(ws + 8388608);     // alias h: second 8 MB
    u16*   xin    = (u16*)  (ws + 16777216);    // 32 MB bf16 [u|z]
    float* u2     = (float*)(ws + 50331648);    // 32 MB f32
    float* xdbc   = (float*)(ws + 83886080);    // 16384x48 f32 (3 MB)
    u16*   dtb    = (u16*)  (ws + 87031808);    // 16 MB bf16
    float* Hin    = (float*)(ws + 103809024);   // 8 MB f32
    float* ypc    = (float*)(ws + 112197632);   // 8x32x512 f32 (512 KB)
    float* pooled = (float*)(ws + 112721920);   // 8x256 f32
    float* feats  = (float*)(ws + 112730112);   // 6x8x256 f32

    // h = x @ W_proj^T + b_proj           (16384,256,K=1024)
    gemm_nt_f32<1,false><<<dim3(1024), 256, 0, stream>>>(x, W_proj, b_proj, h,
        16384, 256, 1024, 1024, 1024, 256);
    // xin = h @ W_in^T (bf16 [u|z])       (16384,1024,K=256)
    gemm_nt_f32<0,true><<<dim3(4096), 256, 0, stream>>>(h, W_in, nullptr, xin,
        16384, 1024, 256, 256, 256, 1024);
    // u2 = silu(causal_conv(u) + conv_b)
    conv_silu<<<dim3(32768), 256, 0, stream>>>(xin, conv_w, conv_b, u2);
    // xdbc = u2 @ W_xp^T                  (16384,48,K=512)
    gemm_nt_f32<0,false><<<dim3(256), 256, 0, stream>>>(u2, W_xp, nullptr, xdbc,
        16384, 48, 512, 512, 512, 48);
    // dt = softplus(xdbc[:,:16] @ W_dt^T + b_dt)  (16384,512,K=16) bf16
    gemm_nt_f32<2,true><<<dim3(2048), 256, 0, stream>>>(xdbc, W_dt, b_dt, dtb,
        16384, 512, 16, 48, 16, 512);

    // chunked selective scan (+u*Dp, *silu(z), pooled over L)
    scan_a<<<dim3(256), 512, 0, stream>>>(dtb, u2, xdbc, A_log, P, S);
    scan_b<<<dim3(256), 256, 0, stream>>>(P, S, Hin);
    scan_c<<<dim3(256), 512, 0, stream>>>(dtb, u2, xdbc, xin, A_log, Dp, Hin, ypc);

    // pooled = (mean_l y) @ W_out^T
    pool_proj<<<dim3(8), 256, 0, stream>>>(ypc, W_out, pooled);

    // head chain (6 sequential stages)
    head_stage_v<true><<<dim3(8), 256, 0, stream>>>(pooled, nullptr, nullptr, nullptr,
        mha_in_w + 512*256, mha_in_b + 512, mha_out_w, mha_out_b, feats);
    for(int i=1;i<6;i++){
        head_stage_v<false><<<dim3(8), 256, 0, stream>>>(pooled, feats + (size_t)(i-1)*2048,
            gate_w + (size_t)(i-1)*256*512, gate_b + (size_t)(i-1)*256,
            mha_in_w + (size_t)i*768*256 + 512*256, mha_in_b + (size_t)i*768 + 512,
            mha_out_w + (size_t)i*256*256, mha_out_b + (size_t)i*256,
            feats + (size_t)i*2048);
    }

    classifier_k<<<dim3(76), 256, 0, stream>>>(feats,
        (const float*)d_in[18], (const float*)d_in[19],
        (const float*)d_in[20], (const float*)d_in[21],
        (const float*)d_in[22], (const float*)d_in[23],
        (const float*)d_in[24], (const float*)d_in[25],
        (const float*)d_in[26], (const float*)d_in[27],
        (const float*)d_in[28], (const float*)d_in[29],
        (float*)d_out);
}

// Round 6
// 657.425 us; speedup vs baseline: 1.2902x; 1.2902x over previous
//
#include <hip/hip_runtime.h>
#include <stdint.h>

typedef unsigned short u16;
typedef uint32_t u32;
typedef __attribute__((ext_vector_type(8))) short bf16x8;
typedef __attribute__((ext_vector_type(4))) float f32x4;

__device__ __forceinline__ float bf2f(u16 u){ return __uint_as_float(((u32)u) << 16); }
__device__ __forceinline__ u16 f2bf(float f){
    u32 u = __float_as_uint(f);
    u += 0x7FFFu + ((u >> 16) & 1u);   // round-to-nearest-even
    return (u16)(u >> 16);
}

#define AS1(p) ((const __attribute__((address_space(1))) void*)(p))
#define AS3(p) ((__attribute__((address_space(3))) void*)(p))

// ---------------------------------------------------------------------------
// Ingest x: f32 -> bf16, 8 elts/thread (16777216 elts)
// ---------------------------------------------------------------------------
__global__ __launch_bounds__(256)
void convert_x(const float* __restrict__ xsrc, u16* __restrict__ dst)
{
    const int i = (blockIdx.x*256 + threadIdx.x)*8;
    const float4 a = *(const float4*)(xsrc + i);
    const float4 b = *(const float4*)(xsrc + i + 4);
    ushort4 o0; o0.x=f2bf(a.x); o0.y=f2bf(a.y); o0.z=f2bf(a.z); o0.w=f2bf(a.w);
    ushort4 o1; o1.x=f2bf(b.x); o1.y=f2bf(b.y); o1.z=f2bf(b.z); o1.w=f2bf(b.w);
    *(ushort4*)(dst+i) = o0; *(ushort4*)(dst+i+4) = o1;
}

// ---------------------------------------------------------------------------
// Convert the 4 GEMM weight matrices to bf16 (W_xp/W_dt zero-padded)
// ---------------------------------------------------------------------------
__global__ __launch_bounds__(256)
void convert_w(const float* __restrict__ W_proj, const float* __restrict__ W_in,
               const float* __restrict__ W_xp, const float* __restrict__ W_dt,
               u16* __restrict__ wproj, u16* __restrict__ win,
               u16* __restrict__ wxpp, u16* __restrict__ wdtp)
{
    const int gid = blockIdx.x*256 + threadIdx.x;
    if(gid < 262144){
        wproj[gid] = f2bf(W_proj[gid]);
    } else if(gid < 786432){
        const int g = gid - 262144;
        win[g] = f2bf(W_in[g]);
    } else if(gid < 851968){
        const int g = gid - 786432;            // 128x512, rows >=48 zero
        const int row = g >> 9;
        wxpp[g] = (row < 48) ? f2bf(W_xp[g]) : (u16)0;
    } else if(gid < 868352){
        const int g = gid - 851968;            // 512x32, k >=16 zero
        const int d = g >> 5, k = g & 31;
        wdtp[g] = (k < 16) ? f2bf(W_dt[d*16 + k]) : (u16)0;
    }
}

// ---------------------------------------------------------------------------
// bf16 MFMA NT GEMM: C[m,n] = sum_k A[m,k]*B[n,k] (+f32 bias) (+softplus)
// BM=BN=128, BK=32, 256 thr (4 waves, each 64x64 via 4x4 mfma 16x16x32).
// Validated numerically (rounds 2/3 bit-identity). bf16 out.
// ---------------------------------------------------------------------------
template<int EPI>   // 0 none, 1 +bias, 2 +bias then softplus
__global__ __launch_bounds__(256)
void gemm_bt(const u16* __restrict__ A, const u16* __restrict__ B,
             const float* __restrict__ bias, u16* __restrict__ C,
             int K, int lda, int ldb, int ldc, int nTilesN)
{
    __shared__ __align__(16) u16 As[128*32];
    __shared__ __align__(16) u16 Bs[128*32];
    const int tid  = threadIdx.x;
    const int bm   = blockIdx.x / nTilesN, bn = blockIdx.x % nTilesN;
    const int m0   = bm*128, n0 = bn*128;
    const int lane = tid & 63, wave = tid >> 6;
    const int r1 = tid >> 2,        p1 = tid & 3;
    const int r2 = (tid+256) >> 2,  p2 = (tid+256) & 3;
    const u16* gA1 = A + (size_t)(m0 + r1)*lda + p1*8;
    const u16* gA2 = A + (size_t)(m0 + r2)*lda + p2*8;
    const u16* gB1 = B + (size_t)(n0 + r1)*ldb + p1*8;
    const u16* gB2 = B + (size_t)(n0 + r2)*ldb + p2*8;
    u16* lA1 = As + wave*512;
    u16* lA2 = As + 2048 + wave*512;
    u16* lB1 = Bs + wave*512;
    u16* lB2 = Bs + 2048 + wave*512;

    f32x4 acc[4][4];
    #pragma unroll
    for(int i=0;i<4;i++)
        #pragma unroll
        for(int j=0;j<4;j++) acc[i][j] = (f32x4){0.f,0.f,0.f,0.f};

    const int wm = (wave>>1)*64, wn = (wave&1)*64;
    const int fr = lane & 15, fq = lane >> 4;

    for(int k0 = 0; k0 < K; k0 += 32){
        __syncthreads();
        __builtin_amdgcn_global_load_lds(AS1(gA1 + k0), AS3(lA1), 16, 0, 0);
        __builtin_amdgcn_global_load_lds(AS1(gA2 + k0), AS3(lA2), 16, 0, 0);
        __builtin_amdgcn_global_load_lds(AS1(gB1 + k0), AS3(lB1), 16, 0, 0);
        __builtin_amdgcn_global_load_lds(AS1(gB2 + k0), AS3(lB2), 16, 0, 0);
        __syncthreads();
        bf16x8 af[4], bw[4];
        #pragma unroll
        for(int i=0;i<4;i++){
            af[i] = *(const bf16x8*)(As + (wm + 16*i + fr)*32 + fq*8);
            bw[i] = *(const bf16x8*)(Bs + (wn + 16*i + fr)*32 + fq*8);
        }
        #pragma unroll
        for(int i=0;i<4;i++)
            #pragma unroll
            for(int j=0;j<4;j++)
                acc[i][j] = __builtin_amdgcn_mfma_f32_16x16x32_bf16(af[i], bw[j], acc[i][j], 0,0,0);
    }

    const int mbase = m0 + wm + fq*4;  // C/D: col=lane&15, row=fq*4+reg
    #pragma unroll
    for(int j=0;j<4;j++){
        const int ncol = n0 + wn + 16*j + fr;
        const float bv = (EPI >= 1) ? bias[ncol] : 0.f;
        #pragma unroll
        for(int i=0;i<4;i++){
            #pragma unroll
            for(int r=0;r<4;r++){
                float v = acc[i][j][r] + bv;
                if(EPI == 2) v = (v > 0.f) ? (v + log1pf(__expf(-v))) : log1pf(__expf(v));
                C[(size_t)(mbase + 16*i + r)*ldc + ncol] = f2bf(v);
            }
        }
    }
}

// ---------------------------------------------------------------------------
// Depthwise causal conv (k=4) + bias + silu. xin bf16 [u|z] -> u2 bf16.
// ---------------------------------------------------------------------------
__global__ __launch_bounds__(256)
void conv_silu(const u16* __restrict__ xin, const float* __restrict__ conv_w,
               const float* __restrict__ conv_b, u16* __restrict__ u2)
{
    const int idx = blockIdx.x*256 + threadIdx.x;   // 8*2048*512
    const int d = idx & 511;
    const int m = idx >> 9;
    const int l = m & 2047;
    const u16* base = xin + (size_t)m*1024 + d;
    float acc = conv_b[d];
    const float w0 = conv_w[d*4+0];
    const float w1 = conv_w[d*4+1];
    const float w2 = conv_w[d*4+2];
    const float w3 = conv_w[d*4+3];
    if(l >= 3) acc += bf2f(base[-3*1024])*w0;
    if(l >= 2) acc += bf2f(base[-2*1024])*w1;
    if(l >= 1) acc += bf2f(base[-1*1024])*w2;
    acc += bf2f(base[0])*w3;
    u2[idx] = f2bf(acc / (1.f + __expf(-acc)));
}

// ---------------------------------------------------------------------------
// Chunked selective scan: 32 chunks x 64 steps. blocks=(b,c), 512 thr = d.
// xdbc is bf16 with row stride 128 ([dt16|B16|C16|pad]).
// ---------------------------------------------------------------------------
__global__ __launch_bounds__(512)
void scan_a(const u16* __restrict__ dtb, const u16* __restrict__ u2,
            const u16* __restrict__ xdbc, const float* __restrict__ A_log,
            float* __restrict__ P, float* __restrict__ S)
{
    const int b = blockIdx.x >> 5, c = blockIdx.x & 31;
    const int d = threadIdx.x;
    const int m0 = b*2048 + c*64;
    __shared__ float Bsh[64][16];
    for(int i = d; i < 1024; i += 512){
        const int tt = i >> 4, n = i & 15;
        Bsh[tt][n] = bf2f(xdbc[(size_t)(m0+tt)*128 + 16 + n]);
    }
    __syncthreads();
    float An[16];
    #pragma unroll
    for(int n=0;n<16;n++) An[n] = -__expf(A_log[d*16+n]);
    float h[16];
    #pragma unroll
    for(int n=0;n<16;n++) h[n] = 0.f;
    float dts = 0.f;
    for(int t=0;t<64;t++){
        const int m = m0 + t;
        const float dtv = bf2f(dtb[(size_t)m*512 + d]);
        const float uv  = bf2f(u2[(size_t)m*512 + d]);
        const float du  = dtv*uv;
        dts += dtv;
        #pragma unroll
        for(int n=0;n<16;n++){
            h[n] = __expf(An[n]*dtv)*h[n] + du*Bsh[t][n];
        }
    }
    const size_t o = ((size_t)(b*32 + c)*512 + d)*16;
    #pragma unroll
    for(int n=0;n<16;n++){ P[o+n] = __expf(An[n]*dts); S[o+n] = h[n]; }
}

__global__ __launch_bounds__(256)
void scan_b(const float* __restrict__ P, const float* __restrict__ S,
            float* __restrict__ Hin)
{
    const int gid = blockIdx.x*256 + threadIdx.x;   // 65536 = 8 * 8192
    const int b = gid >> 13;
    const int dn = gid & 8191;
    float h = 0.f;
    for(int c=0;c<32;c++){
        const size_t o = (size_t)(b*32 + c)*8192 + dn;
        const float t = P[o]*h + S[o];
        Hin[o] = h;
        h = t;
    }
}

__global__ __launch_bounds__(512)
void scan_c(const u16* __restrict__ dtb, const u16* __restrict__ u2,
            const u16* __restrict__ xdbc, const u16* __restrict__ xin,
            const float* __restrict__ A_log, const float* __restrict__ Dp,
            const float* __restrict__ Hin, float* __restrict__ ypc)
{
    const int b = blockIdx.x >> 5, c = blockIdx.x & 31;
    const int d = threadIdx.x;
    const int m0 = b*2048 + c*64;
    __shared__ float Bsh[64][16];
    __shared__ float Csh[64][16];
    for(int i = d; i < 1024; i += 512){
        const int tt = i >> 4, n = i & 15;
        const size_t row = (size_t)(m0+tt)*128;
        Bsh[tt][n] = bf2f(xdbc[row + 16 + n]);
        Csh[tt][n] = bf2f(xdbc[row + 32 + n]);
    }
    __syncthreads();
    float An[16];
    #pragma unroll
    for(int n=0;n<16;n++) An[n] = -__expf(A_log[d*16+n]);
    const float Dpd = Dp[d];
    const size_t ho = ((size_t)(b*32 + c)*512 + d)*16;
    float h[16];
    #pragma unroll
    for(int n=0;n<16;n++) h[n] = Hin[ho+n];
    float ysum = 0.f;
    for(int t=0;t<64;t++){
        const int m = m0 + t;
        const float dtv = bf2f(dtb[(size_t)m*512 + d]);
        const float uv  = bf2f(u2[(size_t)m*512 + d]);
        const float du  = dtv*uv;
        float y = 0.f;
        #pragma unroll
        for(int n=0;n<16;n++){
            h[n] = __expf(An[n]*dtv)*h[n] + du*Bsh[t][n];
            y += h[n]*Csh[t][n];
        }
        y += uv*Dpd;
        const float zv = bf2f(xin[(size_t)m*1024 + 512 + d]);
        y *= zv / (1.f + __expf(-zv));   // * silu(z)
        ysum += y;
    }
    ypc[(size_t)(b*32 + c)*512 + d] = ysum;   // per-chunk partial, no atomics
}

// pooled[b,m] = (sum_c partials)/2048 @ W_out[m,:]  (f32 weights)
__global__ __launch_bounds__(256)
void pool_proj(const float* __restrict__ ypc, const float* __restrict__ W_out,
               float* __restrict__ pooled)
{
    __shared__ float yp[512];
    const int b = blockIdx.x, m = threadIdx.x;
    for(int d = m; d < 512; d += 256){
        float s = 0.f;
        for(int c=0;c<32;c++) s += ypc[(size_t)(b*32 + c)*512 + d];
        yp[d] = s;
    }
    __syncthreads();
    const float* w = W_out + (size_t)m*512;
    float s = 0.f;
    for(int d=0; d<512; d++) s += yp[d]*w[d];
    pooled[b*256 + m] = s*(1.f/2048.f);
}

// ---------------------------------------------------------------------------
// Head stage, VALU f32, one block per batch row, 256 threads = output dim n.
// ---------------------------------------------------------------------------
template<bool FIRST>
__global__ __launch_bounds__(256)
void head_stage_v(const float* __restrict__ pooled, const float* __restrict__ curin,
                  const float* __restrict__ gw, const float* __restrict__ gb,
                  const float* __restrict__ Wv, const float* __restrict__ bv,
                  const float* __restrict__ Wo, const float* __restrict__ bo,
                  float* __restrict__ curout)
{
    const int b = blockIdx.x;       // 8
    const int n = threadIdx.x;      // 256
    __shared__ float sP[256], sC[256], sF[256], sV[256];
    sP[n] = pooled[b*256 + n];
    if(!FIRST) sC[n] = curin[b*256 + n];
    __syncthreads();

    float f;
    if(FIRST){
        f = sP[n];
    } else {
        float g = gb[n];
        const float* w = gw + (size_t)n*512;
        for(int k=0;k<256;k++) g += sC[k]*w[k];
        for(int k=0;k<256;k++) g += sP[k]*w[256+k];
        g = 1.f/(1.f + __expf(-g));
        f = g*sC[n] + (1.f - g)*sP[n];
    }
    sF[n] = f;
    __syncthreads();

    float v = bv[n];
    { const float* w = Wv + (size_t)n*256;
      for(int k=0;k<256;k++) v += sF[k]*w[k]; }
    sV[n] = v;
    __syncthreads();

    float o = bo[n];
    { const float* w = Wo + (size_t)n*256;
      for(int k=0;k<256;k++) o += sV[k]*w[k]; }
    curout[b*256 + n] = o;
}

// ---------------------------------------------------------------------------
// Classifier heads: out_i = feats[i] @ Wc_i^T + bc_i, concat flat, F32 out.
// ---------------------------------------------------------------------------
__global__ __launch_bounds__(256)
void classifier_k(const float* __restrict__ feats,
    const float* __restrict__ W0, const float* __restrict__ b0,
    const float* __restrict__ W1, const float* __restrict__ b1,
    const float* __restrict__ W2, const float* __restrict__ b2,
    const float* __restrict__ W3, const float* __restrict__ b3,
    const float* __restrict__ W4, const float* __restrict__ b4,
    const float* __restrict__ W5, const float* __restrict__ b5,
    float* __restrict__ out)
{
    const int tid = blockIdx.x*256 + threadIdx.x;
    if(tid >= 19320) return;
    const int b  = tid & 7;
    const int ic = tid >> 3;            // 0..2414
    int i, c, nc, ooff;
    const float *W, *bb;
    if(ic < 5)       { i=0; c=ic;      nc=5;    ooff=0;    W=W0; bb=b0; }
    else if(ic<35)   { i=1; c=ic-5;    nc=30;   ooff=40;   W=W1; bb=b1; }
    else if(ic<115)  { i=2; c=ic-35;   nc=80;   ooff=280;  W=W2; bb=b2; }
    else if(ic<315)  { i=3; c=ic-115;  nc=200;  ooff=920;  W=W3; bb=b3; }
    else if(ic<915)  { i=4; c=ic-315;  nc=600;  ooff=2520; W=W4; bb=b4; }
    else             { i=5; c=ic-915;  nc=1500; ooff=7320; W=W5; bb=b5; }
    const float* f = feats + ((size_t)i*8 + b)*256;
    const float* w = W + (size_t)c*256;
    float acc = bb[c];
    for(int m=0;m<256;m++) acc += f[m]*w[m];
    out[ooff + b*nc + c] = acc;
}

extern "C" void kernel_launch(void* const* d_in, const int* in_sizes, int n_in,
                              void* d_out, int out_size, void* d_ws, size_t ws_size,
                              hipStream_t stream)
{
    const float* x         = (const float*)d_in[0];
    const float* W_proj    = (const float*)d_in[1];
    const float* b_proj    = (const float*)d_in[2];
    const float* W_in      = (const float*)d_in[3];
    const float* conv_w    = (const float*)d_in[4];
    const float* conv_b    = (const float*)d_in[5];
    const float* W_xp      = (const float*)d_in[6];
    const float* W_dt      = (const float*)d_in[7];
    const float* b_dt      = (const float*)d_in[8];
    const float* A_log     = (const float*)d_in[9];
    const float* Dp        = (const float*)d_in[10];
    const float* W_out     = (const float*)d_in[11];
    const float* mha_in_w  = (const float*)d_in[12];
    const float* mha_in_b  = (const float*)d_in[13];
    const float* mha_out_w = (const float*)d_in[14];
    const float* mha_out_b = (const float*)d_in[15];
    const float* gate_w    = (const float*)d_in[16];
    const float* gate_b    = (const float*)d_in[17];

    char* ws = (char*)d_ws;
    u16*   xbf    = (u16*)  (ws + 0);           // bf16 x (33.55 MB), dead after GEMM1
    u16*   xin    = (u16*)  (ws + 0);           // alias: [u|z] bf16, written by GEMM2
    u16*   h      = (u16*)  (ws + 33554432);    // bf16 16384x256 (8.39 MB), dead after GEMM2
    float* P      = (float*)(ws + 33554432);    // alias h (8.39 MB)
    u16*   u2     = (u16*)  (ws + 41943040);    // bf16 16384x512 (16.78 MB)
    u16*   xdbc   = (u16*)  (ws + 58720256);    // bf16 16384x128 (4.19 MB)
    u16*   dtb    = (u16*)  (ws + 62914560);    // bf16 16384x512 (16.78 MB)
    float* S      = (float*)(ws + 79691776);    // 8.39 MB
    float* Hin    = (float*)(ws + 88080384);    // 8.39 MB
    float* ypc    = (float*)(ws + 96468992);    // 8x32x512 f32 (512 KB)
    float* pooled = (float*)(ws + 96993280);    // 8x256 f32
    float* feats  = (float*)(ws + 97001472);    // 6x8x256 f32
    u16*   wproj  = (u16*)  (ws + 97058816);    // 256x1024 bf16 (512 KB)
    u16*   win    = (u16*)  (ws + 97583104);    // 1024x256 bf16 (1 MB)
    u16*   wxpp   = (u16*)  (ws + 98631680);    // 128x512 bf16 (128 KB)
    u16*   wdtp   = (u16*)  (ws + 98762752);    // 512x32 bf16 (32 KB)

    convert_x<<<dim3(8192), 256, 0, stream>>>(x, xbf);
    convert_w<<<dim3(3392), 256, 0, stream>>>(W_proj, W_in, W_xp, W_dt,
                                              wproj, win, wxpp, wdtp);

    // h = x @ W_proj^T + b_proj           (16384,256,K=1024)
    gemm_bt<1><<<dim3(128*2), 256, 0, stream>>>(xbf, wproj, b_proj, h,
        1024, 1024, 1024, 256, 2);
    // xin = h @ W_in^T ([u|z])            (16384,1024,K=256) — overwrites xbf (dead)
    gemm_bt<0><<<dim3(128*8), 256, 0, stream>>>(h, win, nullptr, xin,
        256, 256, 256, 1024, 8);
    // u2 = silu(causal_conv(u) + conv_b)
    conv_silu<<<dim3(32768), 256, 0, stream>>>(xin, conv_w, conv_b, u2);
    // xdbc = u2 @ W_xp_pad^T              (16384,128,K=512)
    gemm_bt<0><<<dim3(128), 256, 0, stream>>>(u2, wxpp, nullptr, xdbc,
        512, 512, 512, 128, 1);
    // dt = softplus(xdbc[:, :32] @ W_dt_pad^T + b_dt)   (16384,512,K=32)
    gemm_bt<2><<<dim3(128*4), 256, 0, stream>>>(xdbc, wdtp, b_dt, dtb,
        32, 128, 32, 512, 4);

    // chunked selective scan (+u*Dp, *silu(z), pooled over L)
    scan_a<<<dim3(256), 512, 0, stream>>>(dtb, u2, xdbc, A_log, P, S);
    scan_b<<<dim3(256), 256, 0, stream>>>(P, S, Hin);
    scan_c<<<dim3(256), 512, 0, stream>>>(dtb, u2, xdbc, xin, A_log, Dp, Hin, ypc);

    // pooled = (mean_l y) @ W_out^T
    pool_proj<<<dim3(8), 256, 0, stream>>>(ypc, W_out, pooled);

    // head chain (6 sequential stages)
    head_stage_v<true><<<dim3(8), 256, 0, stream>>>(pooled, nullptr, nullptr, nullptr,
        mha_in_w + 512*256, mha_in_b + 512, mha_out_w, mha_out_b, feats);
    for(int i=1;i<6;i++){
        head_stage_v<false><<<dim3(8), 256, 0, stream>>>(pooled, feats + (size_t)(i-1)*2048,
            gate_w + (size_t)(i-1)*256*512, gate_b + (size_t)(i-1)*256,
            mha_in_w + (size_t)i*768*256 + 512*256, mha_in_b + (size_t)i*768 + 512,
            mha_out_w + (size_t)i*256*256, mha_out_b + (size_t)i*256,
            feats + (size_t)i*2048);
    }

    classifier_k<<<dim3(76), 256, 0, stream>>>(feats,
        (const float*)d_in[18], (const float*)d_in[19],
        (const float*)d_in[20], (const float*)d_in[21],
        (const float*)d_in[22], (const float*)d_in[23],
        (const float*)d_in[24], (const float*)d_in[25],
        (const float*)d_in[26], (const float*)d_in[27],
        (const float*)d_in[28], (const float*)d_in[29],
        (float*)d_out);
}

// Round 7
// 568.300 us; speedup vs baseline: 1.4925x; 1.1568x over previous
//
#include <hip/hip_runtime.h>
#include <stdint.h>

typedef unsigned short u16;
typedef uint32_t u32;
typedef __attribute__((ext_vector_type(8))) short bf16x8;
typedef __attribute__((ext_vector_type(4))) float f32x4;

__device__ __forceinline__ float bf2f(u16 u){ return __uint_as_float(((u32)u) << 16); }
__device__ __forceinline__ u16 f2bf(float f){
    u32 u = __float_as_uint(f);
    u += 0x7FFFu + ((u >> 16) & 1u);   // round-to-nearest-even
    return (u16)(u >> 16);
}

#define AS1(p) ((const __attribute__((address_space(1))) void*)(p))
#define AS3(p) ((__attribute__((address_space(3))) void*)(p))

// whead arena offsets (elements)
#define HW_GATE 0          // 5*256*512
#define HW_WV   655360     // 6*256*256 (mha_in_w rows 512:768 per head)
#define HW_WO   1048576    // 6*256*256
#define HW_TOT  1441792

// ---------------------------------------------------------------------------
// Ingest x: f32 -> bf16, 8 elts/thread (16777216 elts)
// ---------------------------------------------------------------------------
__global__ __launch_bounds__(256)
void convert_x(const float* __restrict__ xsrc, u16* __restrict__ dst)
{
    const int i = (blockIdx.x*256 + threadIdx.x)*8;
    const float4 a = *(const float4*)(xsrc + i);
    const float4 b = *(const float4*)(xsrc + i + 4);
    ushort4 o0; o0.x=f2bf(a.x); o0.y=f2bf(a.y); o0.z=f2bf(a.z); o0.w=f2bf(a.w);
    ushort4 o1; o1.x=f2bf(b.x); o1.y=f2bf(b.y); o1.z=f2bf(b.z); o1.w=f2bf(b.w);
    *(ushort4*)(dst+i) = o0; *(ushort4*)(dst+i+4) = o1;
}

// ---------------------------------------------------------------------------
// Convert GEMM + head weights to bf16 (W_xp zero-padded to 128 rows)
// ---------------------------------------------------------------------------
__global__ __launch_bounds__(256)
void convert_w(const float* __restrict__ W_proj, const float* __restrict__ W_in,
               const float* __restrict__ W_xp,  const float* __restrict__ gate_w,
               const float* __restrict__ mha_in_w, const float* __restrict__ mha_out_w,
               u16* __restrict__ wproj, u16* __restrict__ win,
               u16* __restrict__ wxpp,  u16* __restrict__ whead)
{
    const int gid = blockIdx.x*256 + threadIdx.x;
    if(gid < 262144){
        wproj[gid] = f2bf(W_proj[gid]);
    } else if(gid < 786432){
        const int g = gid - 262144;
        win[g] = f2bf(W_in[g]);
    } else if(gid < 851968){
        const int g = gid - 786432;            // 128x512, rows >=48 zero
        wxpp[g] = ((g >> 9) < 48) ? f2bf(W_xp[g]) : (u16)0;
    } else if(gid < 1507328){
        const int g = gid - 851968;            // gate_w flat (5x256x512)
        whead[HW_GATE + g] = f2bf(gate_w[g]);
    } else if(gid < 1900544){
        const int g = gid - 1507328;           // mha_in_w[i][512+r][k]
        const int i = g >> 16, rk = g & 65535;
        whead[HW_WV + g] = f2bf(mha_in_w[(size_t)i*196608 + 131072 + rk]);
    } else if(gid < 2293760){
        const int g = gid - 1900544;           // mha_out_w flat (6x256x256)
        whead[HW_WO + g] = f2bf(mha_out_w[g]);
    }
}

// ---------------------------------------------------------------------------
// bf16 MFMA NT GEMM (validated): C[m,n]=sum_k A[m,k]*B[n,k] (+f32 bias)
// BM=BN=128, BK=32, 256 thr (4 waves, 64x64 each via 4x4 mfma 16x16x32).
// ---------------------------------------------------------------------------
template<int EPI>   // 0 none, 1 +bias
__global__ __launch_bounds__(256)
void gemm_bt(const u16* __restrict__ A, const u16* __restrict__ B,
             const float* __restrict__ bias, u16* __restrict__ C,
             int K, int lda, int ldb, int ldc, int nTilesN)
{
    __shared__ __align__(16) u16 As[128*32];
    __shared__ __align__(16) u16 Bs[128*32];
    const int tid  = threadIdx.x;
    const int bm   = blockIdx.x / nTilesN, bn = blockIdx.x % nTilesN;
    const int m0   = bm*128, n0 = bn*128;
    const int lane = tid & 63, wave = tid >> 6;
    const int r1 = tid >> 2,        p1 = tid & 3;
    const int r2 = (tid+256) >> 2,  p2 = (tid+256) & 3;
    const u16* gA1 = A + (size_t)(m0 + r1)*lda + p1*8;
    const u16* gA2 = A + (size_t)(m0 + r2)*lda + p2*8;
    const u16* gB1 = B + (size_t)(n0 + r1)*ldb + p1*8;
    const u16* gB2 = B + (size_t)(n0 + r2)*ldb + p2*8;
    u16* lA1 = As + wave*512;
    u16* lA2 = As + 2048 + wave*512;
    u16* lB1 = Bs + wave*512;
    u16* lB2 = Bs + 2048 + wave*512;

    f32x4 acc[4][4];
    #pragma unroll
    for(int i=0;i<4;i++)
        #pragma unroll
        for(int j=0;j<4;j++) acc[i][j] = (f32x4){0.f,0.f,0.f,0.f};

    const int wm = (wave>>1)*64, wn = (wave&1)*64;
    const int fr = lane & 15, fq = lane >> 4;

    for(int k0 = 0; k0 < K; k0 += 32){
        __syncthreads();
        __builtin_amdgcn_global_load_lds(AS1(gA1 + k0), AS3(lA1), 16, 0, 0);
        __builtin_amdgcn_global_load_lds(AS1(gA2 + k0), AS3(lA2), 16, 0, 0);
        __builtin_amdgcn_global_load_lds(AS1(gB1 + k0), AS3(lB1), 16, 0, 0);
        __builtin_amdgcn_global_load_lds(AS1(gB2 + k0), AS3(lB2), 16, 0, 0);
        __syncthreads();
        bf16x8 af[4], bw[4];
        #pragma unroll
        for(int i=0;i<4;i++){
            af[i] = *(const bf16x8*)(As + (wm + 16*i + fr)*32 + fq*8);
            bw[i] = *(const bf16x8*)(Bs + (wn + 16*i + fr)*32 + fq*8);
        }
        #pragma unroll
        for(int i=0;i<4;i++)
            #pragma unroll
            for(int j=0;j<4;j++)
                acc[i][j] = __builtin_amdgcn_mfma_f32_16x16x32_bf16(af[i], bw[j], acc[i][j], 0,0,0);
    }

    const int mbase = m0 + wm + fq*4;  // C/D: col=lane&15, row=fq*4+reg
    #pragma unroll
    for(int j=0;j<4;j++){
        const int ncol = n0 + wn + 16*j + fr;
        const float bv = (EPI >= 1) ? bias[ncol] : 0.f;
        #pragma unroll
        for(int i=0;i<4;i++){
            #pragma unroll
            for(int r=0;r<4;r++){
                C[(size_t)(mbase + 16*i + r)*ldc + ncol] = f2bf(acc[i][j][r] + bv);
            }
        }
    }
}

// ---------------------------------------------------------------------------
// dt kernel: dtb[m,d] = softplus(dot(xdbc[m,0:16], W_dt[d,:]) + b_dt[d])
// W_dt rows in registers; hw-exp/log softplus. 256 blocks x 64 rows.
// ---------------------------------------------------------------------------
__global__ __launch_bounds__(256)
void dt_kernel(const u16* __restrict__ xdbc, const float* __restrict__ W_dt,
               const float* __restrict__ b_dt, u16* __restrict__ dtb)
{
    const int m0 = blockIdx.x*64;
    const int d0 = threadIdx.x;
    float w0[16], w1[16];
    #pragma unroll
    for(int k=0;k<16;k++){ w0[k]=W_dt[d0*16+k]; w1[k]=W_dt[(d0+256)*16+k]; }
    const float bb0=b_dt[d0], bb1=b_dt[d0+256];
    for(int r=0;r<64;r++){
        const int m=m0+r;
        float xv[16];
        #pragma unroll
        for(int k=0;k<16;k++) xv[k]=bf2f(xdbc[(size_t)m*128+k]);
        float a0=bb0, a1=bb1;
        #pragma unroll
        for(int k=0;k<16;k++){ a0+=xv[k]*w0[k]; a1+=xv[k]*w1[k]; }
        a0 = (a0>15.f)? a0 : __logf(1.f+__expf(a0));
        a1 = (a1>15.f)? a1 : __logf(1.f+__expf(a1));
        dtb[(size_t)m*512+d0]     = f2bf(a0);
        dtb[(size_t)m*512+d0+256] = f2bf(a1);
    }
}

// ---------------------------------------------------------------------------
// Depthwise causal conv (k=4) + bias + silu. xin bf16 [u|z] -> u2 bf16.
// ---------------------------------------------------------------------------
__global__ __launch_bounds__(256)
void conv_silu(const u16* __restrict__ xin, const float* __restrict__ conv_w,
               const float* __restrict__ conv_b, u16* __restrict__ u2)
{
    const int idx = blockIdx.x*256 + threadIdx.x;   // 8*2048*512
    const int d = idx & 511;
    const int m = idx >> 9;
    const int l = m & 2047;
    const u16* base = xin + (size_t)m*1024 + d;
    float acc = conv_b[d];
    const float w0 = conv_w[d*4+0];
    const float w1 = conv_w[d*4+1];
    const float w2 = conv_w[d*4+2];
    const float w3 = conv_w[d*4+3];
    if(l >= 3) acc += bf2f(base[-3*1024])*w0;
    if(l >= 2) acc += bf2f(base[-2*1024])*w1;
    if(l >= 1) acc += bf2f(base[-1*1024])*w2;
    acc += bf2f(base[0])*w3;
    u2[idx] = f2bf(acc / (1.f + __expf(-acc)));
}

// ---------------------------------------------------------------------------
// Chunked selective scan: 32 chunks x 64 steps. blocks=(b,c), 512 thr = d.
// ---------------------------------------------------------------------------
__global__ __launch_bounds__(512)
void scan_a(const u16* __restrict__ dtb, const u16* __restrict__ u2,
            const u16* __restrict__ xdbc, const float* __restrict__ A_log,
            float* __restrict__ P, float* __restrict__ S)
{
    const int b = blockIdx.x >> 5, c = blockIdx.x & 31;
    const int d = threadIdx.x;
    const int m0 = b*2048 + c*64;
    __shared__ float Bsh[64][16];
    for(int i = d; i < 1024; i += 512){
        const int tt = i >> 4, n = i & 15;
        Bsh[tt][n] = bf2f(xdbc[(size_t)(m0+tt)*128 + 16 + n]);
    }
    __syncthreads();
    float An[16];
    #pragma unroll
    for(int n=0;n<16;n++) An[n] = -__expf(A_log[d*16+n]);
    float h[16];
    #pragma unroll
    for(int n=0;n<16;n++) h[n] = 0.f;
    float dts = 0.f;
    for(int t=0;t<64;t++){
        const int m = m0 + t;
        const float dtv = bf2f(dtb[(size_t)m*512 + d]);
        const float uv  = bf2f(u2[(size_t)m*512 + d]);
        const float du  = dtv*uv;
        dts += dtv;
        #pragma unroll
        for(int n=0;n<16;n++){
            h[n] = __expf(An[n]*dtv)*h[n] + du*Bsh[t][n];
        }
    }
    const size_t o = ((size_t)(b*32 + c)*512 + d)*16;
    #pragma unroll
    for(int n=0;n<16;n++){ P[o+n] = __expf(An[n]*dts); S[o+n] = h[n]; }
}

__global__ __launch_bounds__(256)
void scan_b(const float* __restrict__ P, const float* __restrict__ S,
            float* __restrict__ Hin)
{
    const int gid = blockIdx.x*256 + threadIdx.x;   // 65536 = 8 * 8192
    const int b = gid >> 13;
    const int dn = gid & 8191;
    float h = 0.f;
    for(int c=0;c<32;c++){
        const size_t o = (size_t)(b*32 + c)*8192 + dn;
        const float t = P[o]*h + S[o];
        Hin[o] = h;
        h = t;
    }
}

__global__ __launch_bounds__(512)
void scan_c(const u16* __restrict__ dtb, const u16* __restrict__ u2,
            const u16* __restrict__ xdbc, const u16* __restrict__ xin,
            const float* __restrict__ A_log, const float* __restrict__ Dp,
            const float* __restrict__ Hin, float* __restrict__ ypc)
{
    const int b = blockIdx.x >> 5, c = blockIdx.x & 31;
    const int d = threadIdx.x;
    const int m0 = b*2048 + c*64;
    __shared__ float Bsh[64][16];
    __shared__ float Csh[64][16];
    for(int i = d; i < 1024; i += 512){
        const int tt = i >> 4, n = i & 15;
        const size_t row = (size_t)(m0+tt)*128;
        Bsh[tt][n] = bf2f(xdbc[row + 16 + n]);
        Csh[tt][n] = bf2f(xdbc[row + 32 + n]);
    }
    __syncthreads();
    float An[16];
    #pragma unroll
    for(int n=0;n<16;n++) An[n] = -__expf(A_log[d*16+n]);
    const float Dpd = Dp[d];
    const size_t ho = ((size_t)(b*32 + c)*512 + d)*16;
    float h[16];
    #pragma unroll
    for(int n=0;n<16;n++) h[n] = Hin[ho+n];
    float ysum = 0.f;
    for(int t=0;t<64;t++){
        const int m = m0 + t;
        const float dtv = bf2f(dtb[(size_t)m*512 + d]);
        const float uv  = bf2f(u2[(size_t)m*512 + d]);
        const float du  = dtv*uv;
        float y = 0.f;
        #pragma unroll
        for(int n=0;n<16;n++){
            h[n] = __expf(An[n]*dtv)*h[n] + du*Bsh[t][n];
            y += h[n]*Csh[t][n];
        }
        y += uv*Dpd;
        const float zv = bf2f(xin[(size_t)m*1024 + 512 + d]);
        y *= zv / (1.f + __expf(-zv));   // * silu(z)
        ysum += y;
    }
    ypc[(size_t)(b*32 + c)*512 + d] = ysum;
}

// pooled[b,m] = (sum_c partials)/2048 @ W_out[m,:]  (f32 weights)
__global__ __launch_bounds__(256)
void pool_proj(const float* __restrict__ ypc, const float* __restrict__ W_out,
               float* __restrict__ pooled)
{
    __shared__ float yp[512];
    const int b = blockIdx.x, m = threadIdx.x;
    for(int d = m; d < 512; d += 256){
        float s = 0.f;
        for(int c=0;c<32;c++) s += ypc[(size_t)(b*32 + c)*512 + d];
        yp[d] = s;
    }
    __syncthreads();
    const float* w = W_out + (size_t)m*512;
    float s = 0.f;
    for(int d=0; d<512; d++) s += yp[d]*w[d];
    pooled[b*256 + m] = s*(1.f/2048.f);
}

// ---------------------------------------------------------------------------
// Fused head chain: all 6 stages, single WG, MFMA (layouts validated r2/r3).
// ---------------------------------------------------------------------------
__global__ __launch_bounds__(256)
void head_chain(const float* __restrict__ pooled, const u16* __restrict__ whead,
                const float* __restrict__ mha_in_b, const float* __restrict__ mha_out_b,
                const float* __restrict__ gate_b, float* __restrict__ feats)
{
    constexpr int S1 = 528, S2 = 272;
    __shared__ __align__(16) u16 A1[16*S1];
    __shared__ __align__(16) u16 A2[16*S2];
    __shared__ __align__(16) u16 A3[16*S2];
    __shared__ float pl[2048];
    __shared__ float cl[2048];
    const int tid = threadIdx.x, lane = tid & 63, wave = tid >> 6;
    const int fr = lane & 15, fq = lane >> 4;
    const int wn = wave*64;

    for(int i=tid;i<2048;i+=256) pl[i] = pooled[i];
    for(int i=tid;i<16*S2;i+=256) A3[i] = 0;
    __syncthreads();
    // stage 0 input: A2 = pooled (padded)
    for(int i=tid;i<16*S2;i+=256){
        const int bi = i/S2, n = i - bi*S2;
        A2[i] = f2bf((bi < 8 && n < 256) ? pl[bi*256+n] : 0.f);
    }
    __syncthreads();

    for(int st=0; st<6; ++st){
        if(st > 0){
            // A1 = [cur | pooled]
            for(int i=tid;i<16*S1;i+=256){
                const int bi = i/S1, n = i - bi*S1;
                float v = 0.f;
                if(bi < 8){
                    if(n < 256)      v = cl[bi*256 + n];
                    else if(n < 512) v = pl[bi*256 + (n-256)];
                }
                A1[i] = f2bf(v);
            }
            __syncthreads();
            f32x4 acc[4];
            #pragma unroll
            for(int j=0;j<4;j++) acc[j] = (f32x4){0.f,0.f,0.f,0.f};
            const u16* gw = whead + HW_GATE + (size_t)(st-1)*131072;
            for(int k0=0;k0<512;k0+=32){
                const bf16x8 af = *(const bf16x8*)(A1 + fr*S1 + k0 + fq*8);
                #pragma unroll
                for(int j=0;j<4;j++){
                    const bf16x8 bw = *(const bf16x8*)(gw + (size_t)(wn+16*j+fr)*512 + k0 + fq*8);
                    acc[j] = __builtin_amdgcn_mfma_f32_16x16x32_bf16(af, bw, acc[j], 0,0,0);
                }
            }
            const float* gb = gate_b + (st-1)*256;
            #pragma unroll
            for(int j=0;j<4;j++){
                const int n = wn + 16*j + fr;
                #pragma unroll
                for(int r=0;r<4;r++){
                    const int bi = fq*4 + r;
                    float f = 0.f;
                    if(bi < 8){
                        const float g = 1.f/(1.f + __expf(-(acc[j][r] + gb[n])));
                        f = g*cl[bi*256+n] + (1.f - g)*pl[bi*256+n];
                    }
                    A2[bi*S2 + n] = f2bf(f);
                }
            }
            __syncthreads();
        }
        {   // v = A2 @ Wv^T + bv
            f32x4 acc[4];
            #pragma unroll
            for(int j=0;j<4;j++) acc[j] = (f32x4){0.f,0.f,0.f,0.f};
            const u16* wv = whead + HW_WV + (size_t)st*65536;
            for(int k0=0;k0<256;k0+=32){
                const bf16x8 af = *(const bf16x8*)(A2 + fr*S2 + k0 + fq*8);
                #pragma unroll
                for(int j=0;j<4;j++){
                    const bf16x8 bw = *(const bf16x8*)(wv + (size_t)(wn+16*j+fr)*256 + k0 + fq*8);
                    acc[j] = __builtin_amdgcn_mfma_f32_16x16x32_bf16(af, bw, acc[j], 0,0,0);
                }
            }
            const float* bv = mha_in_b + st*768 + 512;
            __syncthreads();   // all waves done reading A3 from previous Wo
            #pragma unroll
            for(int j=0;j<4;j++){
                const int n = wn + 16*j + fr;
                #pragma unroll
                for(int r=0;r<4;r++){
                    const int bi = fq*4 + r;
                    A3[bi*S2 + n] = f2bf(bi < 8 ? acc[j][r] + bv[n] : 0.f);
                }
            }
            __syncthreads();
        }
        {   // cur = A3 @ Wo^T + bo
            f32x4 acc[4];
            #pragma unroll
            for(int j=0;j<4;j++) acc[j] = (f32x4){0.f,0.f,0.f,0.f};
            const u16* wo = whead + HW_WO + (size_t)st*65536;
            for(int k0=0;k0<256;k0+=32){
                const bf16x8 af = *(const bf16x8*)(A3 + fr*S2 + k0 + fq*8);
                #pragma unroll
                for(int j=0;j<4;j++){
                    const bf16x8 bw = *(const bf16x8*)(wo + (size_t)(wn+16*j+fr)*256 + k0 + fq*8);
                    acc[j] = __builtin_amdgcn_mfma_f32_16x16x32_bf16(af, bw, acc[j], 0,0,0);
                }
            }
            const float* bo = mha_out_b + st*256;
            __syncthreads();   // all waves done reading A2 (gate of next stage writes it)
            #pragma unroll
            for(int j=0;j<4;j++){
                const int n = wn + 16*j + fr;
                #pragma unroll
                for(int r=0;r<4;r++){
                    const int bi = fq*4 + r;
                    if(bi < 8){
                        const float cv = acc[j][r] + bo[n];
                        cl[bi*256 + n] = cv;
                        feats[(size_t)st*2048 + bi*256 + n] = cv;
                    }
                }
            }
            __syncthreads();
        }
    }
}

// ---------------------------------------------------------------------------
// Classifier heads: out_i = feats[i] @ Wc_i^T + bc_i, concat flat, F32 out.
// ---------------------------------------------------------------------------
__global__ __launch_bounds__(256)
void classifier_k(const float* __restrict__ feats,
    const float* __restrict__ W0, const float* __restrict__ b0,
    const float* __restrict__ W1, const float* __restrict__ b1,
    const float* __restrict__ W2, const float* __restrict__ b2,
    const float* __restrict__ W3, const float* __restrict__ b3,
    const float* __restrict__ W4, const float* __restrict__ b4,
    const float* __restrict__ W5, const float* __restrict__ b5,
    float* __restrict__ out)
{
    const int tid = blockIdx.x*256 + threadIdx.x;
    if(tid >= 19320) return;
    const int b  = tid & 7;
    const int ic = tid >> 3;            // 0..2414
    int i, c, nc, ooff;
    const float *W, *bb;
    if(ic < 5)       { i=0; c=ic;      nc=5;    ooff=0;    W=W0; bb=b0; }
    else if(ic<35)   { i=1; c=ic-5;    nc=30;   ooff=40;   W=W1; bb=b1; }
    else if(ic<115)  { i=2; c=ic-35;   nc=80;   ooff=280;  W=W2; bb=b2; }
    else if(ic<315)  { i=3; c=ic-115;  nc=200;  ooff=920;  W=W3; bb=b3; }
    else if(ic<915)  { i=4; c=ic-315;  nc=600;  ooff=2520; W=W4; bb=b4; }
    else             { i=5; c=ic-915;  nc=1500; ooff=7320; W=W5; bb=b5; }
    const float* f = feats + ((size_t)i*8 + b)*256;
    const float* w = W + (size_t)c*256;
    float acc = bb[c];
    for(int m=0;m<256;m++) acc += f[m]*w[m];
    out[ooff + b*nc + c] = acc;
}

extern "C" void kernel_launch(void* const* d_in, const int* in_sizes, int n_in,
                              void* d_out, int out_size, void* d_ws, size_t ws_size,
                              hipStream_t stream)
{
    const float* x         = (const float*)d_in[0];
    const float* W_proj    = (const float*)d_in[1];
    const float* b_proj    = (const float*)d_in[2];
    const float* W_in      = (const float*)d_in[3];
    const float* conv_w    = (const float*)d_in[4];
    const float* conv_b    = (const float*)d_in[5];
    const float* W_xp      = (const float*)d_in[6];
    const float* W_dt      = (const float*)d_in[7];
    const float* b_dt      = (const float*)d_in[8];
    const float* A_log     = (const float*)d_in[9];
    const float* Dp        = (const float*)d_in[10];
    const float* W_out     = (const float*)d_in[11];
    const float* mha_in_w  = (const float*)d_in[12];
    const float* mha_in_b  = (const float*)d_in[13];
    const float* mha_out_w = (const float*)d_in[14];
    const float* mha_out_b = (const float*)d_in[15];
    const float* gate_w    = (const float*)d_in[16];
    const float* gate_b    = (const float*)d_in[17];

    char* ws = (char*)d_ws;
    u16*   xbf    = (u16*)  (ws + 0);           // bf16 x (33.55 MB), dead after GEMM1
    u16*   xin    = (u16*)  (ws + 0);           // alias: [u|z] bf16, GEMM2 output
    u16*   h      = (u16*)  (ws + 33554432);    // bf16 16384x256 (8.39 MB)
    float* P      = (float*)(ws + 33554432);    // alias h (8.39 MB)
    u16*   u2     = (u16*)  (ws + 41943040);    // bf16 16384x512 (16.78 MB)
    u16*   xdbc   = (u16*)  (ws + 58720256);    // bf16 16384x128 (4.19 MB)
    u16*   dtb    = (u16*)  (ws + 62914560);    // bf16 16384x512 (16.78 MB)
    float* S      = (float*)(ws + 79691776);    // 8.39 MB
    float* Hin    = (float*)(ws + 88080384);    // 8.39 MB
    float* ypc    = (float*)(ws + 96468992);    // 8x32x512 f32 (512 KB)
    float* pooled = (float*)(ws + 96993280);    // 8x256 f32
    float* feats  = (float*)(ws + 97001472);    // 6x8x256 f32
    u16*   wproj  = (u16*)  (ws + 97058816);    // 256x1024 bf16
    u16*   win    = (u16*)  (ws + 97583104);    // 1024x256 bf16
    u16*   wxpp   = (u16*)  (ws + 98631680);    // 128x512 bf16
    u16*   whead  = (u16*)  (ws + 98762752);    // 1441792 bf16 (2.88 MB)

    convert_x<<<dim3(8192), 256, 0, stream>>>(x, xbf);
    convert_w<<<dim3(8960), 256, 0, stream>>>(W_proj, W_in, W_xp, gate_w,
                                              mha_in_w, mha_out_w,
                                              wproj, win, wxpp, whead);

    // h = x @ W_proj^T + b_proj           (16384,256,K=1024)
    gemm_bt<1><<<dim3(128*2), 256, 0, stream>>>(xbf, wproj, b_proj, h,
        1024, 1024, 1024, 256, 2);
    // xin = h @ W_in^T ([u|z])            (16384,1024,K=256) — overwrites xbf
    gemm_bt<0><<<dim3(128*8), 256, 0, stream>>>(h, win, nullptr, xin,
        256, 256, 256, 1024, 8);
    // u2 = silu(causal_conv(u) + conv_b)
    conv_silu<<<dim3(32768), 256, 0, stream>>>(xin, conv_w, conv_b, u2);
    // xdbc = u2 @ W_xp_pad^T              (16384,128,K=512)
    gemm_bt<0><<<dim3(128), 256, 0, stream>>>(u2, wxpp, nullptr, xdbc,
        512, 512, 512, 128, 1);
    // dt = softplus(xdbc[:,:16] @ W_dt^T + b_dt)  — elementwise kernel
    dt_kernel<<<dim3(256), 256, 0, stream>>>(xdbc, W_dt, b_dt, dtb);

    // chunked selective scan (+u*Dp, *silu(z), pooled over L)
    scan_a<<<dim3(256), 512, 0, stream>>>(dtb, u2, xdbc, A_log, P, S);
    scan_b<<<dim3(256), 256, 0, stream>>>(P, S, Hin);
    scan_c<<<dim3(256), 512, 0, stream>>>(dtb, u2, xdbc, xin, A_log, Dp, Hin, ypc);

    // pooled = (mean_l y) @ W_out^T
    pool_proj<<<dim3(8), 256, 0, stream>>>(ypc, W_out, pooled);

    // fused head chain (6 stages, 1 dispatch)
    head_chain<<<dim3(1), 256, 0, stream>>>(pooled, whead, mha_in_b, mha_out_b,
                                            gate_b, feats);

    classifier_k<<<dim3(76), 256, 0, stream>>>(feats,
        (const float*)d_in[18], (const float*)d_in[19],
        (const float*)d_in[20], (const float*)d_in[21],
        (const float*)d_in[22], (const float*)d_in[23],
        (const float*)d_in[24], (const float*)d_in[25],
        (const float*)d_in[26], (const float*)d_in[27],
        (const float*)d_in[28], (const float*)d_in[29],
        (float*)d_out);
}

// Round 8
// 509.440 us; speedup vs baseline: 1.6649x; 1.1155x over previous
//
#include <hip/hip_runtime.h>
#include <stdint.h>

typedef unsigned short u16;
typedef uint32_t u32;
typedef __attribute__((ext_vector_type(8))) short bf16x8;
typedef __attribute__((ext_vector_type(4))) float f32x4;

__device__ __forceinline__ float bf2f(u16 u){ return __uint_as_float(((u32)u) << 16); }
__device__ __forceinline__ u16 f2bf(float f){
    u32 u = __float_as_uint(f);
    u += 0x7FFFu + ((u >> 16) & 1u);   // round-to-nearest-even
    return (u16)(u >> 16);
}

#define AS1(p) ((const __attribute__((address_space(1))) void*)(p))
#define AS3(p) ((__attribute__((address_space(3))) void*)(p))

// whead arena offsets (elements)
#define HW_GATE 0          // 5*256*512
#define HW_WV   655360     // 6*256*256 (mha_in_w rows 512:768 per head)
#define HW_WO   1048576    // 6*256*256
#define HW_TOT  1441792

// ---------------------------------------------------------------------------
// Ingest x: f32 -> bf16, 8 elts/thread (16777216 elts)
// ---------------------------------------------------------------------------
__global__ __launch_bounds__(256)
void convert_x(const float* __restrict__ xsrc, u16* __restrict__ dst)
{
    const int i = (blockIdx.x*256 + threadIdx.x)*8;
    const float4 a = *(const float4*)(xsrc + i);
    const float4 b = *(const float4*)(xsrc + i + 4);
    ushort4 o0; o0.x=f2bf(a.x); o0.y=f2bf(a.y); o0.z=f2bf(a.z); o0.w=f2bf(a.w);
    ushort4 o1; o1.x=f2bf(b.x); o1.y=f2bf(b.y); o1.z=f2bf(b.z); o1.w=f2bf(b.w);
    *(ushort4*)(dst+i) = o0; *(ushort4*)(dst+i+4) = o1;
}

// ---------------------------------------------------------------------------
// Convert GEMM + head weights to bf16 (W_xp zero-padded to 128 rows)
// ---------------------------------------------------------------------------
__global__ __launch_bounds__(256)
void convert_w(const float* __restrict__ W_proj, const float* __restrict__ W_in,
               const float* __restrict__ W_xp,  const float* __restrict__ gate_w,
               const float* __restrict__ mha_in_w, const float* __restrict__ mha_out_w,
               u16* __restrict__ wproj, u16* __restrict__ win,
               u16* __restrict__ wxpp,  u16* __restrict__ whead)
{
    const int gid = blockIdx.x*256 + threadIdx.x;
    if(gid < 262144){
        wproj[gid] = f2bf(W_proj[gid]);
    } else if(gid < 786432){
        const int g = gid - 262144;
        win[g] = f2bf(W_in[g]);
    } else if(gid < 851968){
        const int g = gid - 786432;            // 128x512, rows >=48 zero
        wxpp[g] = ((g >> 9) < 48) ? f2bf(W_xp[g]) : (u16)0;
    } else if(gid < 1507328){
        const int g = gid - 851968;            // gate_w flat (5x256x512)
        whead[HW_GATE + g] = f2bf(gate_w[g]);
    } else if(gid < 1900544){
        const int g = gid - 1507328;           // mha_in_w[i][512+r][k]
        const int i = g >> 16, rk = g & 65535;
        whead[HW_WV + g] = f2bf(mha_in_w[(size_t)i*196608 + 131072 + rk]);
    } else if(gid < 2293760){
        const int g = gid - 1900544;           // mha_out_w flat (6x256x256)
        whead[HW_WO + g] = f2bf(mha_out_w[g]);
    }
}

// ---------------------------------------------------------------------------
// bf16 MFMA NT GEMM (validated): C[m,n]=sum_k A[m,k]*B[n,k] (+f32 bias)
// BM=BN=128, BK=32, 256 thr (4 waves, 64x64 each via 4x4 mfma 16x16x32).
// ---------------------------------------------------------------------------
template<int EPI>   // 0 none, 1 +bias
__global__ __launch_bounds__(256)
void gemm_bt(const u16* __restrict__ A, const u16* __restrict__ B,
             const float* __restrict__ bias, u16* __restrict__ C,
             int K, int lda, int ldb, int ldc, int nTilesN)
{
    __shared__ __align__(16) u16 As[128*32];
    __shared__ __align__(16) u16 Bs[128*32];
    const int tid  = threadIdx.x;
    const int bm   = blockIdx.x / nTilesN, bn = blockIdx.x % nTilesN;
    const int m0   = bm*128, n0 = bn*128;
    const int lane = tid & 63, wave = tid >> 6;
    const int r1 = tid >> 2,        p1 = tid & 3;
    const int r2 = (tid+256) >> 2,  p2 = (tid+256) & 3;
    const u16* gA1 = A + (size_t)(m0 + r1)*lda + p1*8;
    const u16* gA2 = A + (size_t)(m0 + r2)*lda + p2*8;
    const u16* gB1 = B + (size_t)(n0 + r1)*ldb + p1*8;
    const u16* gB2 = B + (size_t)(n0 + r2)*ldb + p2*8;
    u16* lA1 = As + wave*512;
    u16* lA2 = As + 2048 + wave*512;
    u16* lB1 = Bs + wave*512;
    u16* lB2 = Bs + 2048 + wave*512;

    f32x4 acc[4][4];
    #pragma unroll
    for(int i=0;i<4;i++)
        #pragma unroll
        for(int j=0;j<4;j++) acc[i][j] = (f32x4){0.f,0.f,0.f,0.f};

    const int wm = (wave>>1)*64, wn = (wave&1)*64;
    const int fr = lane & 15, fq = lane >> 4;

    for(int k0 = 0; k0 < K; k0 += 32){
        __syncthreads();
        __builtin_amdgcn_global_load_lds(AS1(gA1 + k0), AS3(lA1), 16, 0, 0);
        __builtin_amdgcn_global_load_lds(AS1(gA2 + k0), AS3(lA2), 16, 0, 0);
        __builtin_amdgcn_global_load_lds(AS1(gB1 + k0), AS3(lB1), 16, 0, 0);
        __builtin_amdgcn_global_load_lds(AS1(gB2 + k0), AS3(lB2), 16, 0, 0);
        __syncthreads();
        bf16x8 af[4], bw[4];
        #pragma unroll
        for(int i=0;i<4;i++){
            af[i] = *(const bf16x8*)(As + (wm + 16*i + fr)*32 + fq*8);
            bw[i] = *(const bf16x8*)(Bs + (wn + 16*i + fr)*32 + fq*8);
        }
        #pragma unroll
        for(int i=0;i<4;i++)
            #pragma unroll
            for(int j=0;j<4;j++)
                acc[i][j] = __builtin_amdgcn_mfma_f32_16x16x32_bf16(af[i], bw[j], acc[i][j], 0,0,0);
    }

    const int mbase = m0 + wm + fq*4;  // C/D: col=lane&15, row=fq*4+reg
    #pragma unroll
    for(int j=0;j<4;j++){
        const int ncol = n0 + wn + 16*j + fr;
        const float bv = (EPI >= 1) ? bias[ncol] : 0.f;
        #pragma unroll
        for(int i=0;i<4;i++){
            #pragma unroll
            for(int r=0;r<4;r++){
                C[(size_t)(mbase + 16*i + r)*ldc + ncol] = f2bf(acc[i][j][r] + bv);
            }
        }
    }
}

// ---------------------------------------------------------------------------
// dt kernel: dtb[m,d] = softplus(dot(xdbc[m,0:16], W_dt[d,:]) + b_dt[d])
// ---------------------------------------------------------------------------
__global__ __launch_bounds__(256)
void dt_kernel(const u16* __restrict__ xdbc, const float* __restrict__ W_dt,
               const float* __restrict__ b_dt, u16* __restrict__ dtb)
{
    const int m0 = blockIdx.x*64;
    const int d0 = threadIdx.x;
    float w0[16], w1[16];
    #pragma unroll
    for(int k=0;k<16;k++){ w0[k]=W_dt[d0*16+k]; w1[k]=W_dt[(d0+256)*16+k]; }
    const float bb0=b_dt[d0], bb1=b_dt[d0+256];
    for(int r=0;r<64;r++){
        const int m=m0+r;
        float xv[16];
        #pragma unroll
        for(int k=0;k<16;k++) xv[k]=bf2f(xdbc[(size_t)m*128+k]);
        float a0=bb0, a1=bb1;
        #pragma unroll
        for(int k=0;k<16;k++){ a0+=xv[k]*w0[k]; a1+=xv[k]*w1[k]; }
        a0 = (a0>15.f)? a0 : __logf(1.f+__expf(a0));
        a1 = (a1>15.f)? a1 : __logf(1.f+__expf(a1));
        dtb[(size_t)m*512+d0]     = f2bf(a0);
        dtb[(size_t)m*512+d0+256] = f2bf(a1);
    }
}

// ---------------------------------------------------------------------------
// Depthwise causal conv (k=4) + bias + silu. xin bf16 [u|z] -> u2 bf16.
// ---------------------------------------------------------------------------
__global__ __launch_bounds__(256)
void conv_silu(const u16* __restrict__ xin, const float* __restrict__ conv_w,
               const float* __restrict__ conv_b, u16* __restrict__ u2)
{
    const int idx = blockIdx.x*256 + threadIdx.x;   // 8*2048*512
    const int d = idx & 511;
    const int m = idx >> 9;
    const int l = m & 2047;
    const u16* base = xin + (size_t)m*1024 + d;
    float acc = conv_b[d];
    const float w0 = conv_w[d*4+0];
    const float w1 = conv_w[d*4+1];
    const float w2 = conv_w[d*4+2];
    const float w3 = conv_w[d*4+3];
    if(l >= 3) acc += bf2f(base[-3*1024])*w0;
    if(l >= 2) acc += bf2f(base[-2*1024])*w1;
    if(l >= 1) acc += bf2f(base[-1*1024])*w2;
    acc += bf2f(base[0])*w3;
    u2[idx] = f2bf(acc / (1.f + __expf(-acc)));
}

// ---------------------------------------------------------------------------
// Chunked selective scan: 32 chunks x 64 steps. blocks=(b,c), 512 thr = d.
// ---------------------------------------------------------------------------
__global__ __launch_bounds__(512)
void scan_a(const u16* __restrict__ dtb, const u16* __restrict__ u2,
            const u16* __restrict__ xdbc, const float* __restrict__ A_log,
            float* __restrict__ P, float* __restrict__ S)
{
    const int b = blockIdx.x >> 5, c = blockIdx.x & 31;
    const int d = threadIdx.x;
    const int m0 = b*2048 + c*64;
    __shared__ float Bsh[64][16];
    for(int i = d; i < 1024; i += 512){
        const int tt = i >> 4, n = i & 15;
        Bsh[tt][n] = bf2f(xdbc[(size_t)(m0+tt)*128 + 16 + n]);
    }
    __syncthreads();
    float An[16];
    #pragma unroll
    for(int n=0;n<16;n++) An[n] = -__expf(A_log[d*16+n]);
    float h[16];
    #pragma unroll
    for(int n=0;n<16;n++) h[n] = 0.f;
    float dts = 0.f;
    for(int t=0;t<64;t++){
        const int m = m0 + t;
        const float dtv = bf2f(dtb[(size_t)m*512 + d]);
        const float uv  = bf2f(u2[(size_t)m*512 + d]);
        const float du  = dtv*uv;
        dts += dtv;
        #pragma unroll
        for(int n=0;n<16;n++){
            h[n] = __expf(An[n]*dtv)*h[n] + du*Bsh[t][n];
        }
    }
    const size_t o = ((size_t)(b*32 + c)*512 + d)*16;
    #pragma unroll
    for(int n=0;n<16;n++){ P[o+n] = __expf(An[n]*dts); S[o+n] = h[n]; }
}

__global__ __launch_bounds__(256)
void scan_b(const float* __restrict__ P, const float* __restrict__ S,
            float* __restrict__ Hin)
{
    const int gid = blockIdx.x*256 + threadIdx.x;   // 65536 = 8 * 8192
    const int b = gid >> 13;
    const int dn = gid & 8191;
    float h = 0.f;
    for(int c=0;c<32;c++){
        const size_t o = (size_t)(b*32 + c)*8192 + dn;
        const float t = P[o]*h + S[o];
        Hin[o] = h;
        h = t;
    }
}

__global__ __launch_bounds__(512)
void scan_c(const u16* __restrict__ dtb, const u16* __restrict__ u2,
            const u16* __restrict__ xdbc, const u16* __restrict__ xin,
            const float* __restrict__ A_log, const float* __restrict__ Dp,
            const float* __restrict__ Hin, float* __restrict__ ypc)
{
    const int b = blockIdx.x >> 5, c = blockIdx.x & 31;
    const int d = threadIdx.x;
    const int m0 = b*2048 + c*64;
    __shared__ float Bsh[64][16];
    __shared__ float Csh[64][16];
    for(int i = d; i < 1024; i += 512){
        const int tt = i >> 4, n = i & 15;
        const size_t row = (size_t)(m0+tt)*128;
        Bsh[tt][n] = bf2f(xdbc[row + 16 + n]);
        Csh[tt][n] = bf2f(xdbc[row + 32 + n]);
    }
    __syncthreads();
    float An[16];
    #pragma unroll
    for(int n=0;n<16;n++) An[n] = -__expf(A_log[d*16+n]);
    const float Dpd = Dp[d];
    const size_t ho = ((size_t)(b*32 + c)*512 + d)*16;
    float h[16];
    #pragma unroll
    for(int n=0;n<16;n++) h[n] = Hin[ho+n];
    float ysum = 0.f;
    for(int t=0;t<64;t++){
        const int m = m0 + t;
        const float dtv = bf2f(dtb[(size_t)m*512 + d]);
        const float uv  = bf2f(u2[(size_t)m*512 + d]);
        const float du  = dtv*uv;
        float y = 0.f;
        #pragma unroll
        for(int n=0;n<16;n++){
            h[n] = __expf(An[n]*dtv)*h[n] + du*Bsh[t][n];
            y += h[n]*Csh[t][n];
        }
        y += uv*Dpd;
        const float zv = bf2f(xin[(size_t)m*1024 + 512 + d]);
        y *= zv / (1.f + __expf(-zv));   // * silu(z)
        ysum += y;
    }
    ypc[(size_t)(b*32 + c)*512 + d] = ysum;
}

// pooled[b,m] = (sum_c partials)/2048 @ W_out[m,:]  (f32 weights)
__global__ __launch_bounds__(256)
void pool_proj(const float* __restrict__ ypc, const float* __restrict__ W_out,
               float* __restrict__ pooled)
{
    __shared__ float yp[512];
    const int b = blockIdx.x, m = threadIdx.x;
    for(int d = m; d < 512; d += 256){
        float s = 0.f;
        for(int c=0;c<32;c++) s += ypc[(size_t)(b*32 + c)*512 + d];
        yp[d] = s;
    }
    __syncthreads();
    const float* w = W_out + (size_t)m*512;
    float s = 0.f;
    for(int d=0; d<512; d++) s += yp[d]*w[d];
    pooled[b*256 + m] = s*(1.f/2048.f);
}

// ---------------------------------------------------------------------------
// Fused head chain v2: 1024 thr = 16 waves, each owns a 16-col N-tile.
// Per-phase weight tile (16 rows x K) batch-loaded into registers up front
// (8/16 independent loads in flight per wave) — kills the serialized-latency
// behavior of v1 (151 us @ 4 waves). Same MFMA shapes/order => bit-identical.
// ---------------------------------------------------------------------------
__global__ __launch_bounds__(1024)
void head_chain(const float* __restrict__ pooled, const u16* __restrict__ whead,
                const float* __restrict__ mha_in_b, const float* __restrict__ mha_out_b,
                const float* __restrict__ gate_b, float* __restrict__ feats)
{
    constexpr int S1 = 520, S2 = 264;     // strides (16B-aligned rows)
    __shared__ __align__(16) u16 A1[16*S1];   // gate input [cur|pooled] 16x512
    __shared__ __align__(16) u16 A2[16*S2];   // f matrix 16x256
    __shared__ __align__(16) u16 A3[16*S2];   // v matrix 16x256
    __shared__ float pl[2048], cl[2048];
    const int tid = threadIdx.x, lane = tid & 63, wave = tid >> 6;
    const int fr = lane & 15, fq = lane >> 4;
    const int wn = wave*16;               // this wave's 16-col tile
    const int nn = wn + fr;               // this lane's output column

    for(int i=tid;i<2048;i+=1024) pl[i] = pooled[i];
    for(int i=tid;i<16*S2;i+=1024){       // A2 = bf16(pooled), rows 8..15 = 0
        const int bi = i/S2, n = i - bi*S2;
        A2[i] = f2bf((bi<8 && n<256) ? pooled[bi*256+n] : 0.f);
    }
    for(int i=tid;i<16*S1;i+=1024) A1[i] = 0;
    __syncthreads();

    for(int st=0; st<6; ++st){
        if(st>0){
            // A1 rows 0..7 = [cl | pl]
            for(int i=tid;i<8*S1;i+=1024){
                const int bi = i/S1, n = i - bi*S1;
                float v = 0.f;
                if(n<256)      v = cl[bi*256+n];
                else if(n<512) v = pl[bi*256+(n-256)];
                A1[i] = f2bf(v);
            }
            __syncthreads();
            const u16* gw = whead + HW_GATE + (size_t)(st-1)*131072
                          + (size_t)nn*512 + fq*8;
            bf16x8 bw[16];
            #pragma unroll
            for(int i=0;i<16;i++) bw[i] = *(const bf16x8*)(gw + i*32);
            f32x4 acc = (f32x4){0.f,0.f,0.f,0.f};
            #pragma unroll
            for(int i=0;i<16;i++){
                const bf16x8 af = *(const bf16x8*)(A1 + fr*S1 + i*32 + fq*8);
                acc = __builtin_amdgcn_mfma_f32_16x16x32_bf16(af, bw[i], acc, 0,0,0);
            }
            const float gbv = gate_b[(st-1)*256 + nn];
            #pragma unroll
            for(int r=0;r<4;r++){
                const int bi = fq*4 + r;
                if(bi<8){
                    const float g = 1.f/(1.f + __expf(-(acc[r] + gbv)));
                    A2[bi*S2 + nn] = f2bf(g*cl[bi*256+nn] + (1.f-g)*pl[bi*256+nn]);
                }
            }
            __syncthreads();
        }
        {   // v = A2 @ Wv^T + bv -> A3
            const u16* wv = whead + HW_WV + (size_t)st*65536 + (size_t)nn*256 + fq*8;
            bf16x8 bw[8];
            #pragma unroll
            for(int i=0;i<8;i++) bw[i] = *(const bf16x8*)(wv + i*32);
            f32x4 acc = (f32x4){0.f,0.f,0.f,0.f};
            #pragma unroll
            for(int i=0;i<8;i++){
                const bf16x8 af = *(const bf16x8*)(A2 + fr*S2 + i*32 + fq*8);
                acc = __builtin_amdgcn_mfma_f32_16x16x32_bf16(af, bw[i], acc, 0,0,0);
            }
            const float bvv = mha_in_b[st*768 + 512 + nn];
            #pragma unroll
            for(int r=0;r<4;r++){
                const int bi = fq*4 + r;
                A3[bi*S2 + nn] = f2bf(bi<8 ? acc[r] + bvv : 0.f);
            }
            __syncthreads();
        }
        {   // cur = A3 @ Wo^T + bo -> cl, feats
            const u16* wo = whead + HW_WO + (size_t)st*65536 + (size_t)nn*256 + fq*8;
            bf16x8 bw[8];
            #pragma unroll
            for(int i=0;i<8;i++) bw[i] = *(const bf16x8*)(wo + i*32);
            f32x4 acc = (f32x4){0.f,0.f,0.f,0.f};
            #pragma unroll
            for(int i=0;i<8;i++){
                const bf16x8 af = *(const bf16x8*)(A3 + fr*S2 + i*32 + fq*8);
                acc = __builtin_amdgcn_mfma_f32_16x16x32_bf16(af, bw[i], acc, 0,0,0);
            }
            const float bov = mha_out_b[st*256 + nn];
            #pragma unroll
            for(int r=0;r<4;r++){
                const int bi = fq*4 + r;
                if(bi<8){
                    const float cv = acc[r] + bov;
                    cl[bi*256 + nn] = cv;
                    feats[(size_t)st*2048 + bi*256 + nn] = cv;
                }
            }
            __syncthreads();
        }
    }
}

// ---------------------------------------------------------------------------
// Classifier heads: out_i = feats[i] @ Wc_i^T + bc_i, concat flat, F32 out.
// ---------------------------------------------------------------------------
__global__ __launch_bounds__(256)
void classifier_k(const float* __restrict__ feats,
    const float* __restrict__ W0, const float* __restrict__ b0,
    const float* __restrict__ W1, const float* __restrict__ b1,
    const float* __restrict__ W2, const float* __restrict__ b2,
    const float* __restrict__ W3, const float* __restrict__ b3,
    const float* __restrict__ W4, const float* __restrict__ b4,
    const float* __restrict__ W5, const float* __restrict__ b5,
    float* __restrict__ out)
{
    const int tid = blockIdx.x*256 + threadIdx.x;
    if(tid >= 19320) return;
    const int b  = tid & 7;
    const int ic = tid >> 3;            // 0..2414
    int i, c, nc, ooff;
    const float *W, *bb;
    if(ic < 5)       { i=0; c=ic;      nc=5;    ooff=0;    W=W0; bb=b0; }
    else if(ic<35)   { i=1; c=ic-5;    nc=30;   ooff=40;   W=W1; bb=b1; }
    else if(ic<115)  { i=2; c=ic-35;   nc=80;   ooff=280;  W=W2; bb=b2; }
    else if(ic<315)  { i=3; c=ic-115;  nc=200;  ooff=920;  W=W3; bb=b3; }
    else if(ic<915)  { i=4; c=ic-315;  nc=600;  ooff=2520; W=W4; bb=b4; }
    else             { i=5; c=ic-915;  nc=1500; ooff=7320; W=W5; bb=b5; }
    const float* f = feats + ((size_t)i*8 + b)*256;
    const float* w = W + (size_t)c*256;
    float acc = bb[c];
    for(int m=0;m<256;m++) acc += f[m]*w[m];
    out[ooff + b*nc + c] = acc;
}

extern "C" void kernel_launch(void* const* d_in, const int* in_sizes, int n_in,
                              void* d_out, int out_size, void* d_ws, size_t ws_size,
                              hipStream_t stream)
{
    const float* x         = (const float*)d_in[0];
    const float* W_proj    = (const float*)d_in[1];
    const float* b_proj    = (const float*)d_in[2];
    const float* W_in      = (const float*)d_in[3];
    const float* conv_w    = (const float*)d_in[4];
    const float* conv_b    = (const float*)d_in[5];
    const float* W_xp      = (const float*)d_in[6];
    const float* W_dt      = (const float*)d_in[7];
    const float* b_dt      = (const float*)d_in[8];
    const float* A_log     = (const float*)d_in[9];
    const float* Dp        = (const float*)d_in[10];
    const float* W_out     = (const float*)d_in[11];
    const float* mha_in_w  = (const float*)d_in[12];
    const float* mha_in_b  = (const float*)d_in[13];
    const float* mha_out_w = (const float*)d_in[14];
    const float* mha_out_b = (const float*)d_in[15];
    const float* gate_w    = (const float*)d_in[16];
    const float* gate_b    = (const float*)d_in[17];

    char* ws = (char*)d_ws;
    u16*   xbf    = (u16*)  (ws + 0);           // bf16 x (33.55 MB), dead after GEMM1
    u16*   xin    = (u16*)  (ws + 0);           // alias: [u|z] bf16, GEMM2 output
    u16*   h      = (u16*)  (ws + 33554432);    // bf16 16384x256 (8.39 MB)
    float* P      = (float*)(ws + 33554432);    // alias h (8.39 MB)
    u16*   u2     = (u16*)  (ws + 41943040);    // bf16 16384x512 (16.78 MB)
    u16*   xdbc   = (u16*)  (ws + 58720256);    // bf16 16384x128 (4.19 MB)
    u16*   dtb    = (u16*)  (ws + 62914560);    // bf16 16384x512 (16.78 MB)
    float* S      = (float*)(ws + 79691776);    // 8.39 MB
    float* Hin    = (float*)(ws + 88080384);    // 8.39 MB
    float* ypc    = (float*)(ws + 96468992);    // 8x32x512 f32 (512 KB)
    float* pooled = (float*)(ws + 96993280);    // 8x256 f32
    float* feats  = (float*)(ws + 97001472);    // 6x8x256 f32
    u16*   wproj  = (u16*)  (ws + 97058816);    // 256x1024 bf16
    u16*   win    = (u16*)  (ws + 97583104);    // 1024x256 bf16
    u16*   wxpp   = (u16*)  (ws + 98631680);    // 128x512 bf16
    u16*   whead  = (u16*)  (ws + 98762752);    // 1441792 bf16 (2.88 MB)

    convert_x<<<dim3(8192), 256, 0, stream>>>(x, xbf);
    convert_w<<<dim3(8960), 256, 0, stream>>>(W_proj, W_in, W_xp, gate_w,
                                              mha_in_w, mha_out_w,
                                              wproj, win, wxpp, whead);

    // h = x @ W_proj^T + b_proj           (16384,256,K=1024)
    gemm_bt<1><<<dim3(128*2), 256, 0, stream>>>(xbf, wproj, b_proj, h,
        1024, 1024, 1024, 256, 2);
    // xin = h @ W_in^T ([u|z])            (16384,1024,K=256) — overwrites xbf
    gemm_bt<0><<<dim3(128*8), 256, 0, stream>>>(h, win, nullptr, xin,
        256, 256, 256, 1024, 8);
    // u2 = silu(causal_conv(u) + conv_b)
    conv_silu<<<dim3(32768), 256, 0, stream>>>(xin, conv_w, conv_b, u2);
    // xdbc = u2 @ W_xp_pad^T              (16384,128,K=512)
    gemm_bt<0><<<dim3(128), 256, 0, stream>>>(u2, wxpp, nullptr, xdbc,
        512, 512, 512, 128, 1);
    // dt = softplus(xdbc[:,:16] @ W_dt^T + b_dt)
    dt_kernel<<<dim3(256), 256, 0, stream>>>(xdbc, W_dt, b_dt, dtb);

    // chunked selective scan (+u*Dp, *silu(z), pooled over L)
    scan_a<<<dim3(256), 512, 0, stream>>>(dtb, u2, xdbc, A_log, P, S);
    scan_b<<<dim3(256), 256, 0, stream>>>(P, S, Hin);
    scan_c<<<dim3(256), 512, 0, stream>>>(dtb, u2, xdbc, xin, A_log, Dp, Hin, ypc);

    // pooled = (mean_l y) @ W_out^T
    pool_proj<<<dim3(8), 256, 0, stream>>>(ypc, W_out, pooled);

    // fused head chain (6 stages, 1 dispatch, 16 waves)
    head_chain<<<dim3(1), 1024, 0, stream>>>(pooled, whead, mha_in_b, mha_out_b,
                                             gate_b, feats);

    classifier_k<<<dim3(76), 256, 0, stream>>>(feats,
        (const float*)d_in[18], (const float*)d_in[19],
        (const float*)d_in[20], (const float*)d_in[21],
        (const float*)d_in[22], (const float*)d_in[23],
        (const float*)d_in[24], (const float*)d_in[25],
        (const float*)d_in[26], (const float*)d_in[27],
        (const float*)d_in[28], (const float*)d_in[29],
        (float*)d_out);
}